// Round 5
// baseline (79.085 us; speedup 1.0000x reference)
//
#include <hip/hip_runtime.h>
#include <hip/hip_bf16.h>

// Problem constants
#define BB 8
#define NN 1024
#define FF 2048
#define CC 4
#define HH 1024
#define ROWS (BB * NN)        // 8192
#define MELEMS (8 * FF)       // 16384 folded weights (rows 0-3: p1 (W1a), 4-7: p2 (W1b))

typedef float f4 __attribute__((ext_vector_type(4)));

__device__ __forceinline__ float sigmoidf_fast(float x) {
    return __builtin_amdgcn_rcpf(1.0f + __expf(-x));
}

// Multi-value butterfly: reduce 8 per-lane values across 64 lanes with 10 shuffles.
// Full sum of value index vidx = ((lane&1)<<2) | (lane&2) | ((lane>>2)&1) ends in a[0].
__device__ __forceinline__ float butterfly8(float a[8], int lane) {
    #pragma unroll
    for (int i = 0; i < 4; ++i) {
        float send = (lane & 1) ? a[i] : a[i + 4];
        float got = __shfl_xor(send, 1, 64);
        a[i] = ((lane & 1) ? a[i + 4] : a[i]) + got;
    }
    #pragma unroll
    for (int i = 0; i < 2; ++i) {
        float send = (lane & 2) ? a[i] : a[i + 2];
        float got = __shfl_xor(send, 2, 64);
        a[i] = ((lane & 2) ? a[i + 2] : a[i]) + got;
    }
    {
        float send = (lane & 4) ? a[0] : a[1];
        float got = __shfl_xor(send, 4, 64);
        a[0] = ((lane & 4) ? a[1] : a[0]) + got;
    }
    a[0] += __shfl_xor(a[0], 8, 64);
    a[0] += __shfl_xor(a[0], 16, 64);
    a[0] += __shfl_xor(a[0], 32, 64);
    return a[0];
}

// K1: partial folded weights, float4 over k; spare y-block computes cst.
// Mpart[chunk][half*4+c][f] = sum_{h in chunk} W2[c,h] * W1[h, half*F + f]
__global__ __launch_bounds__(256) void k_fold(const float* __restrict__ W1,
                                              const float* __restrict__ W2,
                                              const float* __restrict__ b1,
                                              const float* __restrict__ b2,
                                              float* __restrict__ Mpart,
                                              float* __restrict__ cst,
                                              int hper, int nchunks) {
    int chunk = blockIdx.y;
    if (chunk == nchunks) {
        // cst[c] = W2[c,:] @ b1 + b2[c]
        if (blockIdx.x != 0) return;
        int t = threadIdx.x;
        int c = t >> 6, lane = t & 63;
        float s = 0.f;
        for (int h = lane; h < HH; h += 64) s += W2[c * HH + h] * b1[h];
        #pragma unroll
        for (int off = 32; off; off >>= 1) s += __shfl_down(s, off);
        if (lane == 0) cst[c] = s + b2[c];
        return;
    }
    int k4 = (blockIdx.x * 256 + threadIdx.x) << 2;   // 0..4092 step 4 (grid.x = 4)
    int half = k4 >> 11;
    int f = k4 & (FF - 1);
    int h0 = chunk * hper;
    f4 a0 = {0.f, 0.f, 0.f, 0.f}, a1 = a0, a2 = a0, a3 = a0;
    const float* base = W1 + (size_t)h0 * (2 * FF) + k4;
    #pragma unroll 4
    for (int i = 0; i < hper; ++i) {
        f4 wv = *(const f4*)(base + (size_t)i * (2 * FF));
        int h = h0 + i;   // uniform per block -> scalar loads of W2
        float s0 = W2[0 * HH + h], s1 = W2[1 * HH + h];
        float s2 = W2[2 * HH + h], s3 = W2[3 * HH + h];
        a0 += wv * s0;
        a1 += wv * s1;
        a2 += wv * s2;
        a3 += wv * s3;
    }
    float* mp = Mpart + (size_t)chunk * MELEMS + (size_t)(half * 4) * FF + f;
    *(f4*)(mp + 0 * FF) = a0;
    *(f4*)(mp + 1 * FF) = a1;
    *(f4*)(mp + 2 * FF) = a2;
    *(f4*)(mp + 3 * FF) = a3;
}

// K1b: reduce partials into M.
__global__ __launch_bounds__(256) void k_reduce(const float* __restrict__ Mpart,
                                                float* __restrict__ M,
                                                int nchunks) {
    int idx = blockIdx.x * 256 + threadIdx.x;   // 0..16383
    float s = 0.f;
    #pragma unroll 8
    for (int p = 0; p < nchunks; ++p) s += Mpart[(size_t)p * MELEMS + idx];
    M[idx] = s;
}

// K2: read-only P1/P2 row-dots (passthrough copy moved to hipMemcpyAsync).
// Thread t owns f-slice [8t, 8t+8). 4 rows/block, 2048 blocks, one sync.
__global__ __launch_bounds__(256) void k_pcompute(const float* __restrict__ v,
                                                  const float* __restrict__ M,
                                                  float* __restrict__ P1,
                                                  float* __restrict__ P2) {
    int t = threadIdx.x;
    int lane = t & 63, wvi = t >> 6;
    int f0 = t * 8;
    float w[8][8];
    #pragma unroll
    for (int j = 0; j < 8; ++j) {
        f4 a = *(const f4*)(M + j * FF + f0);
        f4 b = *(const f4*)(M + j * FF + f0 + 4);
        w[j][0] = a[0]; w[j][1] = a[1]; w[j][2] = a[2]; w[j][3] = a[3];
        w[j][4] = b[0]; w[j][5] = b[1]; w[j][6] = b[2]; w[j][7] = b[3];
    }
    int vidx = ((lane & 1) << 2) | (lane & 2) | ((lane >> 2) & 1);
    __shared__ float red[4][32];
    int row0 = blockIdx.x * 4;

    f4 va[4], vb[4];
    // phase 1: issue all 8 loads back-to-back
    #pragma unroll
    for (int r = 0; r < 4; ++r) {
        const f4* vr = (const f4*)(v + (size_t)(row0 + r) * FF + f0);
        va[r] = vr[0];
        vb[r] = vr[1];
    }
    // phase 2: compute + butterfly reduce
    float fin[4];
    #pragma unroll
    for (int r = 0; r < 4; ++r) {
        float x[8] = {va[r][0], va[r][1], va[r][2], va[r][3],
                      vb[r][0], vb[r][1], vb[r][2], vb[r][3]};
        float acc[8];
        #pragma unroll
        for (int j = 0; j < 8; ++j) {
            float s = 0.f;
            #pragma unroll
            for (int k = 0; k < 8; ++k) s += x[k] * w[j][k];
            acc[j] = s;
        }
        fin[r] = butterfly8(acc, lane);
    }
    if (lane < 8) {
        #pragma unroll
        for (int r = 0; r < 4; ++r) red[r][wvi * 8 + vidx] = fin[r];
    }
    __syncthreads();
    if (t < 32) {
        int r = t >> 3, j = t & 7;
        float s = red[r][j] + red[r][8 + j] + red[r][16 + j] + red[r][24 + j];
        int row = row0 + r;
        if (j < 4) P1[j * ROWS + row] = s;
        else       P2[(j - 4) * ROWS + row] = s;
    }
}

// K3: conn[b][c][j][i] = sigmoid(P1[c][b*N+i] + P2[c][b*N+j] + cst[c])
// 8192 blocks, compile-time 4 unrolled row-iterations for load/store pipelining.
__global__ __launch_bounds__(256) void k_conn(const float* __restrict__ P1,
                                              const float* __restrict__ P2,
                                              const float* __restrict__ cst,
                                              float* __restrict__ out) {
    int t = threadIdx.x;
    #pragma unroll
    for (int it = 0; it < 4; ++it) {
        int r = blockIdx.x + it * 8192;   // 0..32767
        int b = r >> 12;
        int c = (r >> 10) & 3;
        int j = r & (NN - 1);
        float s = P2[c * ROWS + b * NN + j] + cst[c];
        const f4* p1 = (const f4*)(P1 + c * ROWS + b * NN);
        f4 p = p1[t];                 // 256 threads x f4 = 1024 = N
        f4 rs;
        rs[0] = sigmoidf_fast(p[0] + s);
        rs[1] = sigmoidf_fast(p[1] + s);
        rs[2] = sigmoidf_fast(p[2] + s);
        rs[3] = sigmoidf_fast(p[3] + s);
        *((f4*)(out + (size_t)r * NN) + t) = rs;
    }
}

extern "C" void kernel_launch(void* const* d_in, const int* in_sizes, int n_in,
                              void* d_out, int out_size, void* d_ws, size_t ws_size,
                              hipStream_t stream) {
    const float* vectors = (const float*)d_in[0];
    const float* W1 = (const float*)d_in[1];
    const float* b1 = (const float*)d_in[2];
    const float* W2 = (const float*)d_in[3];
    const float* b2 = (const float*)d_in[4];

    float* out_vectors = (float*)d_out;                       // B*N*F floats
    float* out_conn = (float*)d_out + (size_t)ROWS * FF;      // B*C*N*N floats

    // pick fold parallelism by available workspace
    int nchunks = 16;
    {
        size_t fixed = (size_t)MELEMS + 16 + 2 * (size_t)CC * ROWS;
        if (ws_size >= ((size_t)64 * MELEMS + fixed) * sizeof(float)) nchunks = 64;
        else if (ws_size >= ((size_t)32 * MELEMS + fixed) * sizeof(float)) nchunks = 32;
    }
    int hper = HH / nchunks;

    float* w = (float*)d_ws;
    float* Mpart = w;
    float* M     = Mpart + (size_t)nchunks * MELEMS;
    float* cst   = M + MELEMS;
    float* P1    = cst + 16;
    float* P2    = P1 + (size_t)CC * ROWS;

    // Passthrough copy of vectors as a dedicated d2d blit (write-only stream at peak BW)
    hipMemcpyAsync(out_vectors, vectors, (size_t)ROWS * FF * sizeof(float),
                   hipMemcpyDeviceToDevice, stream);

    k_fold<<<dim3(4, nchunks + 1), 256, 0, stream>>>(W1, W2, b1, b2, Mpart, cst, hper, nchunks);
    k_reduce<<<64, 256, 0, stream>>>(Mpart, M, nchunks);
    k_pcompute<<<ROWS / 4, 256, 0, stream>>>(vectors, M, P1, P2);
    k_conn<<<8192, 256, 0, stream>>>(P1, P2, cst, out_conn);
}

// Round 6
// 74.218 us; speedup vs baseline: 1.0656x; 1.0656x over previous
//
#include <hip/hip_runtime.h>
#include <hip/hip_bf16.h>

// Problem constants
#define BB 8
#define NN 1024
#define FF 2048
#define CC 4
#define HH 1024
#define ROWS (BB * NN)        // 8192
#define MELEMS (8 * FF)       // 16384 folded weights (rows 0-3: p1 (W1a), 4-7: p2 (W1b))

typedef float f4 __attribute__((ext_vector_type(4)));

__device__ __forceinline__ float sigmoidf_fast(float x) {
    return __builtin_amdgcn_rcpf(1.0f + __expf(-x));
}

// Butterfly over 4 per-lane values across 64 lanes: 7 shuffles.
// Full sum of value index vidx4 = ((lane&1)<<1) | ((lane>>1)&1) ends in a[0].
__device__ __forceinline__ float butterfly4(float a[4], int lane) {
    #pragma unroll
    for (int i = 0; i < 2; ++i) {
        float send = (lane & 1) ? a[i] : a[i + 2];
        float got = __shfl_xor(send, 1, 64);
        a[i] = ((lane & 1) ? a[i + 2] : a[i]) + got;
    }
    {
        float send = (lane & 2) ? a[0] : a[1];
        float got = __shfl_xor(send, 2, 64);
        a[0] = ((lane & 2) ? a[1] : a[0]) + got;
    }
    a[0] += __shfl_xor(a[0], 4, 64);
    a[0] += __shfl_xor(a[0], 8, 64);
    a[0] += __shfl_xor(a[0], 16, 64);
    a[0] += __shfl_xor(a[0], 32, 64);
    return a[0];
}

// K1: partial folded weights, float4 over k; spare y-block computes cst.
// Mpart[chunk][half*4+c][f] = sum_{h in chunk} W2[c,h] * W1[h, half*F + f]
__global__ __launch_bounds__(256) void k_fold(const float* __restrict__ W1,
                                              const float* __restrict__ W2,
                                              const float* __restrict__ b1,
                                              const float* __restrict__ b2,
                                              float* __restrict__ Mpart,
                                              float* __restrict__ cst,
                                              int hper, int nchunks) {
    int chunk = blockIdx.y;
    if (chunk == nchunks) {
        // cst[c] = W2[c,:] @ b1 + b2[c]
        if (blockIdx.x != 0) return;
        int t = threadIdx.x;
        int c = t >> 6, lane = t & 63;
        float s = 0.f;
        for (int h = lane; h < HH; h += 64) s += W2[c * HH + h] * b1[h];
        #pragma unroll
        for (int off = 32; off; off >>= 1) s += __shfl_down(s, off);
        if (lane == 0) cst[c] = s + b2[c];
        return;
    }
    int k4 = (blockIdx.x * 256 + threadIdx.x) << 2;   // 0..4092 step 4 (grid.x = 4)
    int half = k4 >> 11;
    int f = k4 & (FF - 1);
    int h0 = chunk * hper;
    f4 a0 = {0.f, 0.f, 0.f, 0.f}, a1 = a0, a2 = a0, a3 = a0;
    const float* base = W1 + (size_t)h0 * (2 * FF) + k4;
    #pragma unroll 4
    for (int i = 0; i < hper; ++i) {
        f4 wv = *(const f4*)(base + (size_t)i * (2 * FF));
        int h = h0 + i;   // uniform per block -> scalar loads of W2
        float s0 = W2[0 * HH + h], s1 = W2[1 * HH + h];
        float s2 = W2[2 * HH + h], s3 = W2[3 * HH + h];
        a0 += wv * s0;
        a1 += wv * s1;
        a2 += wv * s2;
        a3 += wv * s3;
    }
    float* mp = Mpart + (size_t)chunk * MELEMS + (size_t)(half * 4) * FF + f;
    *(f4*)(mp + 0 * FF) = a0;
    *(f4*)(mp + 1 * FF) = a1;
    *(f4*)(mp + 2 * FF) = a2;
    *(f4*)(mp + 3 * FF) = a3;
}

// K1b: reduce partials into M.
__global__ __launch_bounds__(256) void k_reduce(const float* __restrict__ Mpart,
                                                float* __restrict__ M,
                                                int nchunks) {
    int idx = blockIdx.x * 256 + threadIdx.x;   // 0..16383
    float s = 0.f;
    #pragma unroll 8
    for (int p = 0; p < nchunks; ++p) s += Mpart[(size_t)p * MELEMS + idx];
    M[idx] = s;
}

// K2: P1/P2 row-dots + fused vectors passthrough.
// Thread t owns f-slice [8t, 8t+8). 8 rows/block in 2 batches of 4.
// j split into two passes of 4 so only w[4][8] (32 VGPR) is live at a time:
// peak ~95 VGPR -> 4+ waves/SIMD (R3's w[8][8] variant sat at ~130 -> 3).
// One __syncthreads per batch via double-buffered red[].
__global__ __launch_bounds__(256) void k_pcompute(const float* __restrict__ v,
                                                  const float* __restrict__ M,
                                                  float* __restrict__ outv,
                                                  float* __restrict__ P1,
                                                  float* __restrict__ P2) {
    int t = threadIdx.x;
    int lane = t & 63, wvi = t >> 6;
    int f0 = t * 8;
    int vidx4 = ((lane & 1) << 1) | ((lane >> 1) & 1);
    __shared__ float red[2][4][32];
    int row0 = blockIdx.x * 8;

    #pragma unroll
    for (int batch = 0; batch < 2; ++batch) {
        int rb = row0 + batch * 4;
        f4 va[4], vb[4];
        // phase 1: issue all 8 row loads back-to-back (128 B/lane in flight)
        #pragma unroll
        for (int r = 0; r < 4; ++r) {
            const f4* vr = (const f4*)(v + (size_t)(rb + r) * FF + f0);
            va[r] = vr[0];
            vb[r] = vr[1];
        }
        // phase 2: passthrough stores
        #pragma unroll
        for (int r = 0; r < 4; ++r) {
            f4* po = (f4*)(outv + (size_t)(rb + r) * FF + f0);
            po[0] = va[r];
            po[1] = vb[r];
        }
        // phase 3: two j-passes, w[4][8] live at a time
        #pragma unroll
        for (int pass = 0; pass < 2; ++pass) {
            float w[4][8];
            #pragma unroll
            for (int j = 0; j < 4; ++j) {
                f4 a = *(const f4*)(M + (pass * 4 + j) * FF + f0);
                f4 b = *(const f4*)(M + (pass * 4 + j) * FF + f0 + 4);
                w[j][0] = a[0]; w[j][1] = a[1]; w[j][2] = a[2]; w[j][3] = a[3];
                w[j][4] = b[0]; w[j][5] = b[1]; w[j][6] = b[2]; w[j][7] = b[3];
            }
            #pragma unroll
            for (int r = 0; r < 4; ++r) {
                float acc[4];
                #pragma unroll
                for (int j = 0; j < 4; ++j) {
                    float s = 0.f;
                    #pragma unroll
                    for (int k = 0; k < 4; ++k) {
                        s += va[r][k] * w[j][k];
                        s += vb[r][k] * w[j][k + 4];
                    }
                    acc[j] = s;
                }
                float fin = butterfly4(acc, lane);
                if (lane < 4) red[batch][r][wvi * 8 + pass * 4 + vidx4] = fin;
            }
        }
        __syncthreads();
        if (t < 32) {
            int r = t >> 3, j = t & 7;
            float s = red[batch][r][j] + red[batch][r][8 + j] +
                      red[batch][r][16 + j] + red[batch][r][24 + j];
            int row = rb + r;
            if (j < 4) P1[j * ROWS + row] = s;
            else       P2[(j - 4) * ROWS + row] = s;
        }
    }
}

// K3: conn[b][c][j][i] = sigmoid(P1[c][b*N+i] + P2[c][b*N+j] + cst[c])
// 8192 blocks; 4 consecutive j per block share (b,c): P1 row loaded once,
// P2 scalars as one f4, 16 KB contiguous stores per block.
__global__ __launch_bounds__(256) void k_conn(const float* __restrict__ P1,
                                              const float* __restrict__ P2,
                                              const float* __restrict__ cst,
                                              float* __restrict__ out) {
    int t = threadIdx.x;
    int base = blockIdx.x * 4;            // rr = base..base+3, same (b,c)
    int b = base >> 12;
    int c = (base >> 10) & 3;
    int j0 = base & (NN - 1);             // multiple of 4
    float cc = cst[c];
    f4 p = ((const f4*)(P1 + c * ROWS + b * NN))[t];   // 256 threads x f4 = row
    f4 s4 = *(const f4*)(P2 + c * ROWS + b * NN + j0);
    #pragma unroll
    for (int it = 0; it < 4; ++it) {
        float s = s4[it] + cc;
        f4 rs;
        rs[0] = sigmoidf_fast(p[0] + s);
        rs[1] = sigmoidf_fast(p[1] + s);
        rs[2] = sigmoidf_fast(p[2] + s);
        rs[3] = sigmoidf_fast(p[3] + s);
        *((f4*)(out + (size_t)(base + it) * NN) + t) = rs;
    }
}

extern "C" void kernel_launch(void* const* d_in, const int* in_sizes, int n_in,
                              void* d_out, int out_size, void* d_ws, size_t ws_size,
                              hipStream_t stream) {
    const float* vectors = (const float*)d_in[0];
    const float* W1 = (const float*)d_in[1];
    const float* b1 = (const float*)d_in[2];
    const float* W2 = (const float*)d_in[3];
    const float* b2 = (const float*)d_in[4];

    float* out_vectors = (float*)d_out;                       // B*N*F floats
    float* out_conn = (float*)d_out + (size_t)ROWS * FF;      // B*C*N*N floats

    // pick fold parallelism by available workspace
    int nchunks = 16;
    {
        size_t fixed = (size_t)MELEMS + 16 + 2 * (size_t)CC * ROWS;
        if (ws_size >= ((size_t)64 * MELEMS + fixed) * sizeof(float)) nchunks = 64;
        else if (ws_size >= ((size_t)32 * MELEMS + fixed) * sizeof(float)) nchunks = 32;
    }
    int hper = HH / nchunks;

    float* w = (float*)d_ws;
    float* Mpart = w;
    float* M     = Mpart + (size_t)nchunks * MELEMS;
    float* cst   = M + MELEMS;
    float* P1    = cst + 16;
    float* P2    = P1 + (size_t)CC * ROWS;

    k_fold<<<dim3(4, nchunks + 1), 256, 0, stream>>>(W1, W2, b1, b2, Mpart, cst, hper, nchunks);
    k_reduce<<<64, 256, 0, stream>>>(Mpart, M, nchunks);
    k_pcompute<<<ROWS / 8, 256, 0, stream>>>(vectors, M, out_vectors, P1, P2);
    k_conn<<<8192, 256, 0, stream>>>(P1, P2, cst, out_conn);
}